// Round 2
// baseline (743.330 us; speedup 1.0000x reference)
//
#include <hip/hip_runtime.h>
#include <cstdint>

typedef unsigned short u16;
typedef unsigned int   u32;
typedef __bf16 bf16x8 __attribute__((ext_vector_type(8)));
typedef float  f32x4  __attribute__((ext_vector_type(4)));

#define NCTX 10
#define BSZ  32
#define IDF  256
#define QSZ  1024
#define CDF  512
#define LSZ  128

__device__ __forceinline__ u16 f2bf(float f) {
    u32 u = __float_as_uint(f);
    u += 0x7FFFu + ((u >> 16) & 1u);          // RNE to bf16
    return (u16)(u >> 16);
}
__device__ __forceinline__ float bf2f(u16 h) {
    return __uint_as_float(((u32)h) << 16);
}

union U4V { uint4 u; bf16x8 v; };

__device__ __forceinline__ bf16x8 ldg16(const u16* p) {   // 8 contiguous bf16 (16B)
    U4V t; t.u = *(const uint4*)p; return t.v;
}
__device__ __forceinline__ bf16x8 pack8(const float* f) { // 8 f32 -> bf16x8 (RNE)
    U4V t;
    t.u.x = (u32)f2bf(f[0]) | ((u32)f2bf(f[1]) << 16);
    t.u.y = (u32)f2bf(f[2]) | ((u32)f2bf(f[3]) << 16);
    t.u.z = (u32)f2bf(f[4]) | ((u32)f2bf(f[5]) << 16);
    t.u.w = (u32)f2bf(f[6]) | ((u32)f2bf(f[7]) << 16);
    return t.v;
}
__device__ __forceinline__ f32x4 mfma16(bf16x8 a, bf16x8 b, f32x4 c) {
    return __builtin_amdgcn_mfma_f32_16x16x32_bf16(a, b, c, 0, 0, 0);
}

// ---------------- K1a: weights -> bf16 (Wc hi/lo, Wcat plain) ----------------
__global__ __launch_bounds__(256) void k1a_conv(const float* __restrict__ Wc,
                                                const float* __restrict__ Wcat,
                                                u16* __restrict__ Wc_hi,
                                                u16* __restrict__ Wc_lo,
                                                u16* __restrict__ Wcat_bf) {
    int i = blockIdx.x * 256 + threadIdx.x;
    if (i < IDF * CDF) {
        float f = Wc[i];
        u16 h = f2bf(f);
        Wc_hi[i] = h;
        Wc_lo[i] = f2bf(f - bf2f(h));
    } else {
        int j = i - IDF * CDF;
        Wcat_bf[j] = f2bf(Wcat[j]);
    }
}

// ---------------- K1b: input [B,idf,Q] -> T_hi/T_lo [B,Q,idf] ----------------
__global__ __launch_bounds__(256) void k1b_tgt(const float* __restrict__ input,
                                               u16* __restrict__ T_hi,
                                               u16* __restrict__ T_lo) {
    __shared__ float t[32][33];
    const int tx = threadIdx.x, ty = threadIdx.y;
    const int qt = blockIdx.x, dt = blockIdx.y, b = blockIdx.z;
#pragma unroll
    for (int k = 0; k < 4; ++k)
        t[ty + 8 * k][tx] = input[((long)b * IDF + dt * 32 + ty + 8 * k) * QSZ + qt * 32 + tx];
    __syncthreads();
#pragma unroll
    for (int k = 0; k < 4; ++k) {
        int q = qt * 32 + ty + 8 * k;
        float f = t[tx][ty + 8 * k];
        u16 h = f2bf(f);
        long o = ((long)b * QSZ + q) * IDF + dt * 32 + tx;
        T_hi[o] = h;
        T_lo[o] = f2bf(f - bf2f(h));
    }
}

// ---------------- K1c: contexts [n,b,c,l] -> ctxT bf16 [n,b,l,c] -------------
__global__ __launch_bounds__(256) void k1c_ctx(const float* __restrict__ ctx,
                                               u16* __restrict__ ctxT) {
    __shared__ float t[32][33];
    const int tx = threadIdx.x, ty = threadIdx.y;
    const int lt = blockIdx.x, ct = blockIdx.y, nb = blockIdx.z;
    const long ib = (long)nb * CDF * LSZ;
#pragma unroll
    for (int k = 0; k < 4; ++k)
        t[ty + 8 * k][tx] = ctx[ib + (long)(ct * 32 + ty + 8 * k) * LSZ + lt * 32 + tx];
    __syncthreads();
    const long ob = (long)nb * LSZ * CDF;
#pragma unroll
    for (int k = 0; k < 4; ++k)
        ctxT[ob + (long)(lt * 32 + ty + 8 * k) * CDF + ct * 32 + tx] = f2bf(t[tx][ty + 8 * k]);
}

// ---------------- K2: sourceT = Wc @ ctx  (per (n,b), hi/lo x hi) ------------
// C[d,l], M=128 tile (2 blocks/batch), N=128, K=512.
// Outputs: sTT_hi/lo [nb][l][d] (scores B-operand), s_dl [nb][d][l] (PV B-operand)
__global__ __launch_bounds__(256, 2) void k2_src(const u16* __restrict__ Wc_hi,
                                                 const u16* __restrict__ Wc_lo,
                                                 const u16* __restrict__ ctxT,
                                                 u16* __restrict__ sTT_hi,
                                                 u16* __restrict__ sTT_lo,
                                                 u16* __restrict__ s_dl) {
    __shared__ u16 bounce[128 * 136];
    const int tid = threadIdx.x;
    const int L = tid & 63, w = tid >> 6;
    const int wd = w >> 1, wl = w & 1, lr = L & 15, quad = L >> 4;
    const int dbase = blockIdx.x * 128;
    const int nb = blockIdx.y;
    const u16* ctxb = ctxT + (long)nb * LSZ * CDF;

    const f32x4 vz = {0.f, 0.f, 0.f, 0.f};
    f32x4 acc[4][4];
#pragma unroll
    for (int m = 0; m < 4; ++m)
#pragma unroll
        for (int nn = 0; nn < 4; ++nn) acc[m][nn] = vz;

    for (int kc = 0; kc < 16; ++kc) {
        const int c0 = kc * 32 + quad * 8;
        bf16x8 aH[4], aL[4], bb[4];
#pragma unroll
        for (int m = 0; m < 4; ++m) {
            const int d = dbase + 64 * wd + 16 * m + lr;
            aH[m] = ldg16(Wc_hi + d * CDF + c0);
            aL[m] = ldg16(Wc_lo + d * CDF + c0);
        }
#pragma unroll
        for (int nn = 0; nn < 4; ++nn) {
            const int l = 64 * wl + 16 * nn + lr;
            bb[nn] = ldg16(ctxb + l * CDF + c0);
        }
#pragma unroll
        for (int m = 0; m < 4; ++m)
#pragma unroll
            for (int nn = 0; nn < 4; ++nn) {
                acc[m][nn] = mfma16(aH[m], bb[nn], acc[m][nn]);
                acc[m][nn] = mfma16(aL[m], bb[nn], acc[m][nn]);
            }
    }

    // ---- epilogue: 3 LDS-bounce passes for coalesced stores ----
    // Each 128-row segment is 128 u16 = 16 uint4 stores per row -> 2048 stores.
    // pass 1: hi, transposed [l][d]
#pragma unroll
    for (int m = 0; m < 4; ++m)
#pragma unroll
        for (int nn = 0; nn < 4; ++nn)
#pragma unroll
            for (int r = 0; r < 4; ++r) {
                const int d = 64 * wd + 16 * m + 4 * quad + r;
                const int l = 64 * wl + 16 * nn + lr;
                bounce[l * 136 + d] = f2bf(acc[m][nn][r]);
            }
    __syncthreads();
    for (int i = tid; i < 2048; i += 256) {
        const int l = i >> 4, g = (i & 15) * 8;
        *(uint4*)(sTT_hi + ((long)nb * LSZ + l) * IDF + dbase + g) =
            *(const uint4*)(bounce + l * 136 + g);
    }
    __syncthreads();
    // pass 2: lo, transposed [l][d]
#pragma unroll
    for (int m = 0; m < 4; ++m)
#pragma unroll
        for (int nn = 0; nn < 4; ++nn)
#pragma unroll
            for (int r = 0; r < 4; ++r) {
                const int d = 64 * wd + 16 * m + 4 * quad + r;
                const int l = 64 * wl + 16 * nn + lr;
                float c = acc[m][nn][r];
                u16 h = f2bf(c);
                bounce[l * 136 + d] = f2bf(c - bf2f(h));
            }
    __syncthreads();
    for (int i = tid; i < 2048; i += 256) {
        const int l = i >> 4, g = (i & 15) * 8;
        *(uint4*)(sTT_lo + ((long)nb * LSZ + l) * IDF + dbase + g) =
            *(const uint4*)(bounce + l * 136 + g);
    }
    __syncthreads();
    // pass 3: hi, natural [d][l]
#pragma unroll
    for (int m = 0; m < 4; ++m)
#pragma unroll
        for (int nn = 0; nn < 4; ++nn)
#pragma unroll
            for (int r = 0; r < 4; ++r) {
                const int d = 64 * wd + 16 * m + 4 * quad + r;
                const int l = 64 * wl + 16 * nn + lr;
                bounce[d * 136 + l] = f2bf(acc[m][nn][r]);
            }
    __syncthreads();
    for (int i = tid; i < 2048; i += 256) {
        const int d = i >> 4, g = (i & 15) * 8;
        *(uint4*)(s_dl + ((long)nb * IDF + dbase + d) * LSZ + g) =
            *(const uint4*)(bounce + d * 136 + g);
    }
}

// ---------------- K3: fused scores->softmax->PV->concat-proj->LN -------------
// One block per (b, 64-row q tile); loops n=0..9; X accumulated in registers.
__global__ __launch_bounds__(256, 2) void k3_attn(
    const u16* __restrict__ T_hi, const u16* __restrict__ T_lo,
    const u16* __restrict__ sTT_hi, const u16* __restrict__ sTT_lo,
    const u16* __restrict__ s_dl, const u16* __restrict__ Wcat_bf,
    const float* __restrict__ Wb, const float* __restrict__ gam_p,
    const float* __restrict__ bet_p, float* __restrict__ out)
{
    __shared__ float S[64 * 132];      // scores fp32; overlaid later by attn bf16 [64][264]
    __shared__ float redA[64 * 4];
    __shared__ float redB[64 * 4];
    u16* attnL = (u16*)S;

    const int tid = threadIdx.x;
    const int L = tid & 63, w = tid >> 6;
    const int wq = w >> 1, wh = w & 1, lr = L & 15, quad = L >> 4;
    const int b = blockIdx.y;
    const int bq = b * QSZ + blockIdx.x * 64;

    const f32x4 vz = {0.f, 0.f, 0.f, 0.f};
    f32x4 x_acc[2][8];
#pragma unroll
    for (int m = 0; m < 2; ++m)
#pragma unroll
        for (int nn = 0; nn < 8; ++nn) x_acc[m][nn] = vz;

    for (int n = 0; n < NCTX; ++n) {
        const int nb = n * BSZ + b;
        const u16* sttH = sTT_hi + (long)nb * (LSZ * IDF);
        const u16* sttL = sTT_lo + (long)nb * (LSZ * IDF);
        const u16* sdl  = s_dl  + (long)nb * (IDF * LSZ);
        const u16* wcat = Wcat_bf + n * IDF;

        // ---- phase 1: S[64q x 128l] = (T_hi+T_lo) . (sTT_hi+sTT_lo)^T, drop lo*lo
        f32x4 s_acc[2][4];
#pragma unroll
        for (int m = 0; m < 2; ++m)
#pragma unroll
            for (int nn = 0; nn < 4; ++nn) s_acc[m][nn] = vz;

        for (int kc = 0; kc < 8; ++kc) {
            const int c0 = kc * 32 + quad * 8;
            bf16x8 aH[2], aL[2], bH[4], bL[4];
#pragma unroll
            for (int m = 0; m < 2; ++m) {
                const int ro = (bq + 32 * wq + 16 * m + lr) * IDF + c0;
                aH[m] = ldg16(T_hi + ro);
                aL[m] = ldg16(T_lo + ro);
            }
#pragma unroll
            for (int nn = 0; nn < 4; ++nn) {
                const int ro = (64 * wh + 16 * nn + lr) * IDF + c0;
                bH[nn] = ldg16(sttH + ro);
                bL[nn] = ldg16(sttL + ro);
            }
#pragma unroll
            for (int m = 0; m < 2; ++m)
#pragma unroll
                for (int nn = 0; nn < 4; ++nn) {
                    s_acc[m][nn] = mfma16(aH[m], bH[nn], s_acc[m][nn]);
                    s_acc[m][nn] = mfma16(aH[m], bL[nn], s_acc[m][nn]);
                    s_acc[m][nn] = mfma16(aL[m], bH[nn], s_acc[m][nn]);
                }
        }
        __syncthreads();   // prev-n attn-LDS reads done before S overwrite
#pragma unroll
        for (int m = 0; m < 2; ++m)
#pragma unroll
            for (int nn = 0; nn < 4; ++nn)
#pragma unroll
                for (int r = 0; r < 4; ++r)
                    S[(32 * wq + 16 * m + 4 * quad + r) * 132 + 64 * wh + 16 * nn + lr] =
                        s_acc[m][nn][r];
        __syncthreads();

        // ---- softmax over l (per row, 4 threads/row); keep UNNORMALIZED exp in S
        {
            const int row = tid >> 2, sg = (tid & 3) * 32;
            float* sp = S + row * 132 + sg;
            float mx = sp[0];
#pragma unroll
            for (int i = 1; i < 32; ++i) mx = fmaxf(mx, sp[i]);
            redA[row * 4 + (tid & 3)] = mx;
            __syncthreads();
            const float rm = fmaxf(fmaxf(redA[row * 4], redA[row * 4 + 1]),
                                   fmaxf(redA[row * 4 + 2], redA[row * 4 + 3]));
            float sm = 0.f;
#pragma unroll
            for (int i = 0; i < 32; ++i) {
                float e = __expf(sp[i] - rm);
                sp[i] = e;
                sm += e;
            }
            redB[row * 4 + (tid & 3)] = sm;
            __syncthreads();
        }

        // ---- phase 2: attn[64q x 256d] = E . s_dl^T  (unnormalized)
        f32x4 a_acc[2][8];
#pragma unroll
        for (int m = 0; m < 2; ++m)
#pragma unroll
            for (int nn = 0; nn < 8; ++nn) a_acc[m][nn] = vz;

        for (int kc = 0; kc < 4; ++kc) {
            const int l0 = kc * 32 + quad * 8;
            bf16x8 af[2];
#pragma unroll
            for (int m = 0; m < 2; ++m)
                af[m] = pack8(S + (32 * wq + 16 * m + lr) * 132 + l0);
#pragma unroll
            for (int nn = 0; nn < 8; ++nn) {
                const int d = 128 * wh + 16 * nn + lr;
                bf16x8 bf = ldg16(sdl + d * LSZ + l0);
#pragma unroll
                for (int m = 0; m < 2; ++m)
                    a_acc[m][nn] = mfma16(af[m], bf, a_acc[m][nn]);
            }
        }
        __syncthreads();   // all S reads done before attn overlay

        float invr[2][4];
#pragma unroll
        for (int m = 0; m < 2; ++m)
#pragma unroll
            for (int r = 0; r < 4; ++r) {
                const int row = 32 * wq + 16 * m + 4 * quad + r;
                invr[m][r] = 1.0f / (redB[row * 4] + redB[row * 4 + 1] +
                                     redB[row * 4 + 2] + redB[row * 4 + 3]);
            }
#pragma unroll
        for (int m = 0; m < 2; ++m)
#pragma unroll
            for (int nn = 0; nn < 8; ++nn)
#pragma unroll
                for (int r = 0; r < 4; ++r) {
                    const int row = 32 * wq + 16 * m + 4 * quad + r;
                    const int col = 128 * wh + 16 * nn + lr;
                    attnL[row * 264 + col] = f2bf(a_acc[m][nn][r] * invr[m][r]);
                }
        __syncthreads();

        // ---- phase 3: X[64q x 256e] += attn . Wcat_n^T
        for (int kc = 0; kc < 8; ++kc) {
            const int d0 = kc * 32 + quad * 8;
            bf16x8 af[2];
#pragma unroll
            for (int m = 0; m < 2; ++m) {
                U4V t;
                t.u = *(const uint4*)(attnL + (32 * wq + 16 * m + lr) * 264 + d0);
                af[m] = t.v;
            }
#pragma unroll
            for (int nn = 0; nn < 8; ++nn) {
                const int e = 128 * wh + 16 * nn + lr;
                bf16x8 bf = ldg16(wcat + e * (NCTX * IDF) + d0);
#pragma unroll
                for (int m = 0; m < 2; ++m)
                    x_acc[m][nn] = mfma16(af[m], bf, x_acc[m][nn]);
            }
        }
        // no sync needed: next iteration's first sync guards the S overwrite
    }

    // ---- epilogue: bias + relu + residual + LayerNorm(eps=0) ----
    float gv[8], bv[8], wv[8];
    int ec[8];
#pragma unroll
    for (int nn = 0; nn < 8; ++nn) {
        ec[nn] = 128 * wh + 16 * nn + lr;
        wv[nn] = Wb[ec[nn]];
        gv[nn] = gam_p[ec[nn]];
        bv[nn] = bet_p[ec[nn]];
    }
#pragma unroll
    for (int m = 0; m < 2; ++m)
#pragma unroll
        for (int r = 0; r < 4; ++r) {
            const int row = 32 * wq + 16 * m + 4 * quad + r;
            const u16* th = T_hi + (bq + row) * IDF;
            const u16* tl = T_lo + (bq + row) * IDF;
#pragma unroll
            for (int nn = 0; nn < 8; ++nn) {
                float resid = bf2f(th[ec[nn]]) + bf2f(tl[ec[nn]]);   // ~fp32-exact target
                x_acc[m][nn][r] = fmaxf(x_acc[m][nn][r] + wv[nn], 0.f) + resid;
            }
        }
    float s1[2][4], s2[2][4];
#pragma unroll
    for (int m = 0; m < 2; ++m)
#pragma unroll
        for (int r = 0; r < 4; ++r) {
            float a = 0.f, q2 = 0.f;
#pragma unroll
            for (int nn = 0; nn < 8; ++nn) {
                float v = x_acc[m][nn][r];
                a += v;
                q2 += v * v;
            }
            s1[m][r] = a;
            s2[m][r] = q2;
        }
#pragma unroll
    for (int off = 1; off <= 8; off <<= 1)
#pragma unroll
        for (int m = 0; m < 2; ++m)
#pragma unroll
            for (int r = 0; r < 4; ++r) {
                s1[m][r] += __shfl_xor(s1[m][r], off);
                s2[m][r] += __shfl_xor(s2[m][r], off);
            }
    if (lr == 0) {
#pragma unroll
        for (int m = 0; m < 2; ++m)
#pragma unroll
            for (int r = 0; r < 4; ++r) {
                const int row = 32 * wq + 16 * m + 4 * quad + r;
                redA[row * 4 + wh * 2]     = s1[m][r];
                redA[row * 4 + wh * 2 + 1] = s2[m][r];
            }
    }
    __syncthreads();
#pragma unroll
    for (int m = 0; m < 2; ++m)
#pragma unroll
        for (int r = 0; r < 4; ++r) {
            const int row = 32 * wq + 16 * m + 4 * quad + r;
            const float S1 = redA[row * 4] + redA[row * 4 + 2];
            const float S2 = redA[row * 4 + 1] + redA[row * 4 + 3];
            const float mu = S1 * (1.f / 256.f);
            const float rs = rsqrtf(S2 * (1.f / 256.f) - mu * mu);
            float* op = out + (long)(bq + row) * IDF;
#pragma unroll
            for (int nn = 0; nn < 8; ++nn)
                op[ec[nn]] = (x_acc[m][nn][r] - mu) * rs * gv[nn] + bv[nn];
        }
}

// ---------------- launch ----------------
extern "C" void kernel_launch(void* const* d_in, const int* in_sizes, int n_in,
                              void* d_out, int out_size, void* d_ws, size_t ws_size,
                              hipStream_t stream) {
    const float* input    = (const float*)d_in[0];
    const float* contexts = (const float*)d_in[1];
    const float* Wc       = (const float*)d_in[2];
    const float* Wcat     = (const float*)d_in[3];
    const float* Wb       = (const float*)d_in[4];
    const float* gamma    = (const float*)d_in[5];
    const float* beta     = (const float*)d_in[6];
    float* out = (float*)d_out;

    char* ws = (char*)d_ws;
    size_t off = 0;
    u16* Wc_hi   = (u16*)(ws + off); off += (size_t)IDF * CDF * 2;          // 256 KB
    u16* Wc_lo   = (u16*)(ws + off); off += (size_t)IDF * CDF * 2;          // 256 KB
    u16* Wcat_bf = (u16*)(ws + off); off += (size_t)IDF * NCTX * IDF * 2;   // 1.25 MB
    u16* T_hi    = (u16*)(ws + off); off += (size_t)BSZ * QSZ * IDF * 2;    // 16.8 MB
    u16* T_lo    = (u16*)(ws + off); off += (size_t)BSZ * QSZ * IDF * 2;    // 16.8 MB
    u16* ctxT    = (u16*)(ws + off); off += (size_t)NCTX * BSZ * LSZ * CDF * 2; // 41.9 MB
    u16* sTT_hi  = (u16*)(ws + off); off += (size_t)NCTX * BSZ * LSZ * IDF * 2; // 21.0 MB
    u16* sTT_lo  = (u16*)(ws + off); off += (size_t)NCTX * BSZ * LSZ * IDF * 2; // 21.0 MB
    u16* s_dl    = (u16*)(ws + off); off += (size_t)NCTX * BSZ * IDF * LSZ * 2; // 21.0 MB
    (void)in_sizes; (void)n_in; (void)out_size; (void)ws_size;

    k1a_conv<<<3072, 256, 0, stream>>>(Wc, Wcat, Wc_hi, Wc_lo, Wcat_bf);
    k1b_tgt<<<dim3(QSZ / 32, IDF / 32, BSZ), dim3(32, 8), 0, stream>>>(input, T_hi, T_lo);
    k1c_ctx<<<dim3(LSZ / 32, CDF / 32, NCTX * BSZ), dim3(32, 8), 0, stream>>>(contexts, ctxT);
    k2_src<<<dim3(2, NCTX * BSZ), 256, 0, stream>>>(Wc_hi, Wc_lo, ctxT, sTT_hi, sTT_lo, s_dl);
    k3_attn<<<dim3(QSZ / 64, BSZ), 256, 0, stream>>>(T_hi, T_lo, sTT_hi, sTT_lo, s_dl,
                                                     Wcat_bf, Wb, gamma, beta, out);
}